// Round 1
// baseline (2776.531 us; speedup 1.0000x reference)
//
#include <hip/hip_runtime.h>

#define N_NODES 100000
#define N_EDGES 1600000
#define D 128

// ---------------- Kernel 1: LayerNorm + ReLU (one wave per row, 4 rows/block) ----
__global__ __launch_bounds__(256) void ln_relu_kernel(
    const float* __restrict__ x, const float* __restrict__ gamma,
    const float* __restrict__ beta, float* __restrict__ h)
{
    int row  = blockIdx.x * 4 + (threadIdx.x >> 6);
    int lane = threadIdx.x & 63;
    const float* xr = x + (size_t)row * D;
    float2 v = *(const float2*)(xr + lane * 2);
    float s  = v.x + v.y;
    float sq = v.x * v.x + v.y * v.y;
#pragma unroll
    for (int m = 32; m >= 1; m >>= 1) {
        s  += __shfl_xor(s, m);
        sq += __shfl_xor(sq, m);
    }
    float mu   = s * (1.0f / D);
    float var  = sq * (1.0f / D) - mu * mu;
    float rstd = rsqrtf(var + 1e-5f);
    float g0 = gamma[lane * 2], g1 = gamma[lane * 2 + 1];
    float b0 = beta[lane * 2],  b1 = beta[lane * 2 + 1];
    float h0 = fmaxf(fmaf((v.x - mu) * rstd, g0, b0), 0.0f);
    float h1 = fmaxf(fmaf((v.y - mu) * rstd, g1, b1), 0.0f);
    *(float2*)(h + (size_t)row * D + lane * 2) = make_float2(h0, h1);
}

// ---------------- Kernel 1b: detect edge dtype (int64 vs int32 view) ------------
// If buffer is little-endian int64 with values < 2^31, every odd int32 word of the
// first 64 entries is 0. Probability of false positive with real int32 ids ~1e-320.
__global__ void detect_kernel(const int* __restrict__ e, int* __restrict__ flag)
{
    int z = 1;
    for (int i = 1; i < 128; i += 2) z &= (e[i] == 0) ? 1 : 0;
    *flag = z;  // 1 => int64 layout
}

// ---------------- Kernel 1c: convert edges to int32 -----------------------------
__global__ __launch_bounds__(256) void convert_edges_kernel(
    const void* __restrict__ e, const int* __restrict__ flag, int* __restrict__ out)
{
    int i = blockIdx.x * 256 + threadIdx.x;   // exactly 2*N_EDGES threads
    if (*flag) out[i] = (int)((const long long*)e)[i];
    else       out[i] = ((const int*)e)[i];
}

// ---------------- Kernel 2: edge gather + scatter-add ----------------------------
// 32 lanes per edge, float4 per lane. msg = relu(h[src]) but h >= 0 already.
__global__ __launch_bounds__(256) void scatter_kernel(
    const float* __restrict__ h, const int* __restrict__ ei, float* __restrict__ aggr)
{
    unsigned int gid = blockIdx.x * 256u + threadIdx.x;
    unsigned int e = gid >> 5;
    unsigned int c = (gid & 31u) << 2;
    int s = ei[e];
    int d = ei[N_EDGES + e];
    float4 v = *(const float4*)(h + (size_t)s * D + c);
    float* o = aggr + (size_t)d * D + c;
    atomicAdd(o + 0, v.x);
    atomicAdd(o + 1, v.y);
    atomicAdd(o + 2, v.z);
    atomicAdd(o + 3, v.w);
}

// ---------------- Kernel 3: out = ((1+eps)h + aggr) @ W^T + b + x ---------------
// Block = 256 threads, 32 rows x 128 cols tile, 4x4 register tile per thread.
// K split into two halves of 64 so static LDS stays under 64 KB.
// aggr aliases `out`: each block reads only the 32 rows it later writes.
__global__ __launch_bounds__(256) void out_gemm_kernel(
    const float* __restrict__ h, const float* __restrict__ aggr,
    const float* __restrict__ x, const float* __restrict__ W,
    const float* __restrict__ bias, const float* __restrict__ eps_p,
    float* __restrict__ out)
{
    __shared__ float lds_w[64 * 129];  // Wt[kk][d], stride 129 -> conflict-free reads
    __shared__ float lds_t[32 * 68];   // t[row][kk], stride 68 (16B-aligned, conflict-free)
    const int tid = threadIdx.x;
    const int dl  = tid & 31;
    const int rg  = tid >> 5;
    const int row0 = blockIdx.x * 32;
    const float ep1 = 1.0f + eps_p[0];
    float acc[4][4] = {};

    for (int kh = 0; kh < 2; ++kh) {
        if (kh) __syncthreads();
        // stage W^T half: source W[d][kh*64 + kk], d=0..127, kk=0..63
#pragma unroll
        for (int it = 0; it < 8; ++it) {
            int idx4 = tid + it * 256;
            int d   = idx4 >> 4;
            int kk0 = (idx4 & 15) * 4;
            float4 w4 = *(const float4*)(W + (size_t)d * D + kh * 64 + kk0);
            lds_w[(kk0 + 0) * 129 + d] = w4.x;
            lds_w[(kk0 + 1) * 129 + d] = w4.y;
            lds_w[(kk0 + 2) * 129 + d] = w4.z;
            lds_w[(kk0 + 3) * 129 + d] = w4.w;
        }
        // stage t half: t = (1+eps)*h + aggr for rows row0..row0+31
#pragma unroll
        for (int it = 0; it < 2; ++it) {
            int idx4 = tid + it * 256;
            int row = idx4 >> 4;
            int kk0 = (idx4 & 15) * 4;
            size_t off = (size_t)(row0 + row) * D + kh * 64 + kk0;
            float4 hv = *(const float4*)(h + off);
            float4 av = *(const float4*)(aggr + off);
            float4 t4;
            t4.x = fmaf(ep1, hv.x, av.x);
            t4.y = fmaf(ep1, hv.y, av.y);
            t4.z = fmaf(ep1, hv.z, av.z);
            t4.w = fmaf(ep1, hv.w, av.w);
            *(float4*)(&lds_t[row * 68 + kk0]) = t4;
        }
        __syncthreads();

        for (int kk = 0; kk < 64; ++kk) {
            float tv[4], wv[4];
#pragma unroll
            for (int i = 0; i < 4; ++i) tv[i] = lds_t[(rg * 4 + i) * 68 + kk];
#pragma unroll
            for (int j = 0; j < 4; ++j) wv[j] = lds_w[kk * 129 + dl + 32 * j];
#pragma unroll
            for (int i = 0; i < 4; ++i)
#pragma unroll
                for (int j = 0; j < 4; ++j)
                    acc[i][j] = fmaf(tv[i], wv[j], acc[i][j]);
        }
    }

    // epilogue: + bias + residual x
#pragma unroll
    for (int i = 0; i < 4; ++i) {
        int n = row0 + rg * 4 + i;
        const float* xr = x + (size_t)n * D;
        float* orow = out + (size_t)n * D;
#pragma unroll
        for (int j = 0; j < 4; ++j) {
            int d = dl + 32 * j;
            orow[d] = acc[i][j] + bias[d] + xr[d];
        }
    }
}

extern "C" void kernel_launch(void* const* d_in, const int* in_sizes, int n_in,
                              void* d_out, int out_size, void* d_ws, size_t ws_size,
                              hipStream_t stream)
{
    const float* x     = (const float*)d_in[0];
    const void*  ei    = d_in[1];
    const float* gamma = (const float*)d_in[2];
    const float* beta  = (const float*)d_in[3];
    const float* W     = (const float*)d_in[4];
    const float* bias  = (const float*)d_in[5];
    const float* eps_p = (const float*)d_in[6];
    float* out = (float*)d_out;

    float* h       = (float*)d_ws;                                    // 51.2 MB
    int*   edges32 = (int*)((char*)d_ws + (size_t)N_NODES * D * 4);   // 12.8 MB
    int*   flag    = (int*)((char*)d_ws + (size_t)N_NODES * D * 4
                            + (size_t)2 * N_EDGES * 4);

    ln_relu_kernel<<<N_NODES / 4, 256, 0, stream>>>(x, gamma, beta, h);
    detect_kernel<<<1, 1, 0, stream>>>((const int*)ei, flag);
    convert_edges_kernel<<<(2 * N_EDGES) / 256, 256, 0, stream>>>(ei, flag, edges32);
    hipMemsetAsync(d_out, 0, (size_t)out_size * sizeof(float), stream);
    scatter_kernel<<<(N_EDGES * 32) / 256, 256, 0, stream>>>(h, edges32, out);
    out_gemm_kernel<<<N_NODES / 32, 256, 0, stream>>>(h, out, x, W, bias, eps_p, out);
}

// Round 2
// 399.031 us; speedup vs baseline: 6.9582x; 6.9582x over previous
//
#include <hip/hip_runtime.h>

#define N_NODES 100000
#define N_EDGES 1600000
#define D 128

// ---------------- Kernel 1: LayerNorm + ReLU (one wave per row, 4 rows/block) ----
__global__ __launch_bounds__(256) void ln_relu_kernel(
    const float* __restrict__ x, const float* __restrict__ gamma,
    const float* __restrict__ beta, float* __restrict__ h)
{
    int row  = blockIdx.x * 4 + (threadIdx.x >> 6);
    int lane = threadIdx.x & 63;
    const float* xr = x + (size_t)row * D;
    float2 v = *(const float2*)(xr + lane * 2);
    float s  = v.x + v.y;
    float sq = v.x * v.x + v.y * v.y;
#pragma unroll
    for (int m = 32; m >= 1; m >>= 1) {
        s  += __shfl_xor(s, m);
        sq += __shfl_xor(sq, m);
    }
    float mu   = s * (1.0f / D);
    float var  = sq * (1.0f / D) - mu * mu;
    float rstd = rsqrtf(var + 1e-5f);
    float g0 = gamma[lane * 2], g1 = gamma[lane * 2 + 1];
    float b0 = beta[lane * 2],  b1 = beta[lane * 2 + 1];
    float h0 = fmaxf(fmaf((v.x - mu) * rstd, g0, b0), 0.0f);
    float h1 = fmaxf(fmaf((v.y - mu) * rstd, g1, b1), 0.0f);
    *(float2*)(h + (size_t)row * D + lane * 2) = make_float2(h0, h1);
}

// ---------------- Kernel 1b: detect edge dtype (int64 vs int32 view) ------------
__global__ void detect_kernel(const int* __restrict__ e, int* __restrict__ flag)
{
    int z = 1;
    for (int i = 1; i < 128; i += 2) z &= (e[i] == 0) ? 1 : 0;
    *flag = z;  // 1 => int64 layout
}

// ---------------- Kernel 1c: convert edges to int32 -----------------------------
__global__ __launch_bounds__(256) void convert_edges_kernel(
    const void* __restrict__ e, const int* __restrict__ flag, int* __restrict__ out)
{
    int i = blockIdx.x * 256 + threadIdx.x;   // exactly 2*N_EDGES threads
    if (*flag) out[i] = (int)((const long long*)e)[i];
    else       out[i] = ((const int*)e)[i];
}

// ---------------- Kernel 2a: histogram of destinations ---------------------------
__global__ __launch_bounds__(256) void hist_kernel(
    const int* __restrict__ ei, int* __restrict__ counts)
{
    int e = blockIdx.x * 256 + threadIdx.x;
    atomicAdd(&counts[ei[N_EDGES + e]], 1);
}

// ---------------- Kernel 2b: per-block exclusive scan (chunk = 256) --------------
__global__ __launch_bounds__(256) void scan_partial_kernel(
    const int* __restrict__ counts, int* __restrict__ pre, int* __restrict__ bsum)
{
    int i = blockIdx.x * 256 + threadIdx.x;
    int v = (i < N_NODES) ? counts[i] : 0;
    int lane = threadIdx.x & 63, w = threadIdx.x >> 6;
    int s = v;
#pragma unroll
    for (int m = 1; m < 64; m <<= 1) {
        int t = __shfl_up(s, m);
        if (lane >= m) s += t;
    }
    __shared__ int wsum[4];
    if (lane == 63) wsum[w] = s;
    __syncthreads();
    if (threadIdx.x == 0) {
        int a = 0;
#pragma unroll
        for (int k = 0; k < 4; ++k) { int t = wsum[k]; wsum[k] = a; a += t; }
        bsum[blockIdx.x] = a;
    }
    __syncthreads();
    if (i < N_NODES) pre[i] = wsum[w] + (s - v);  // block-local exclusive
}

// ---------------- Kernel 2c: scan the 391 block sums (single block) --------------
__global__ __launch_bounds__(512) void scan_block_kernel(int* __restrict__ bsum, int nb)
{
    int i = threadIdx.x;
    int v = (i < nb) ? bsum[i] : 0;
    int lane = i & 63, w = i >> 6;
    int s = v;
#pragma unroll
    for (int m = 1; m < 64; m <<= 1) {
        int t = __shfl_up(s, m);
        if (lane >= m) s += t;
    }
    __shared__ int wsum[8];
    if (lane == 63) wsum[w] = s;
    __syncthreads();
    if (i == 0) {
        int a = 0;
#pragma unroll
        for (int k = 0; k < 8; ++k) { int t = wsum[k]; wsum[k] = a; a += t; }
    }
    __syncthreads();
    if (i < nb) bsum[i] = wsum[w] + (s - v);
}

// ---------------- Kernel 2d: offsets = pre + bsum; cursor = offsets ---------------
__global__ __launch_bounds__(256) void finalize_kernel(
    const int* __restrict__ pre, const int* __restrict__ bsum,
    int* __restrict__ offsets, int* __restrict__ cursor)
{
    int i = blockIdx.x * 256 + threadIdx.x;
    if (i < N_NODES) {
        int o = pre[i] + bsum[i >> 8];
        offsets[i] = o;
        cursor[i]  = o;
    } else if (i == N_NODES) {
        offsets[i] = N_EDGES;
    }
}

// ---------------- Kernel 2e: place src ids into dst-sorted order ------------------
__global__ __launch_bounds__(256) void place_kernel(
    const int* __restrict__ ei, int* __restrict__ cursor, int* __restrict__ sorted_src)
{
    int e = blockIdx.x * 256 + threadIdx.x;
    int d = ei[N_EDGES + e];
    int pos = atomicAdd(&cursor[d], 1);
    sorted_src[pos] = ei[e];
}

// ---------------- Kernel 2f: segment sum (pull) — one wave per node ---------------
// msg = relu(h[src]) = h[src] since h >= 0. aggr row written exactly once.
__global__ __launch_bounds__(256) void segsum_kernel(
    const float* __restrict__ h, const int* __restrict__ offsets,
    const int* __restrict__ sorted_src, float* __restrict__ aggr)
{
    int n    = blockIdx.x * 4 + (threadIdx.x >> 6);
    int lane = threadIdx.x & 63;
    int e    = offsets[n];
    int eend = offsets[n + 1];
    float2 acc = make_float2(0.0f, 0.0f);
    for (; e + 4 <= eend; e += 4) {
        int s0 = sorted_src[e + 0];
        int s1 = sorted_src[e + 1];
        int s2 = sorted_src[e + 2];
        int s3 = sorted_src[e + 3];
        float2 v0 = *(const float2*)(h + (size_t)s0 * D + lane * 2);
        float2 v1 = *(const float2*)(h + (size_t)s1 * D + lane * 2);
        float2 v2 = *(const float2*)(h + (size_t)s2 * D + lane * 2);
        float2 v3 = *(const float2*)(h + (size_t)s3 * D + lane * 2);
        acc.x += (v0.x + v1.x) + (v2.x + v3.x);
        acc.y += (v0.y + v1.y) + (v2.y + v3.y);
    }
    for (; e < eend; ++e) {
        int s = sorted_src[e];
        float2 v = *(const float2*)(h + (size_t)s * D + lane * 2);
        acc.x += v.x;
        acc.y += v.y;
    }
    *(float2*)(aggr + (size_t)n * D + lane * 2) = acc;
}

// ---------------- Kernel 3: out = ((1+eps)h + aggr) @ W^T + b + x ---------------
__global__ __launch_bounds__(256) void out_gemm_kernel(
    const float* __restrict__ h, const float* __restrict__ aggr,
    const float* __restrict__ x, const float* __restrict__ W,
    const float* __restrict__ bias, const float* __restrict__ eps_p,
    float* __restrict__ out)
{
    __shared__ float lds_w[64 * 129];
    __shared__ float lds_t[32 * 68];
    const int tid = threadIdx.x;
    const int dl  = tid & 31;
    const int rg  = tid >> 5;
    const int row0 = blockIdx.x * 32;
    const float ep1 = 1.0f + eps_p[0];
    float acc[4][4] = {};

    for (int kh = 0; kh < 2; ++kh) {
        if (kh) __syncthreads();
#pragma unroll
        for (int it = 0; it < 8; ++it) {
            int idx4 = tid + it * 256;
            int d   = idx4 >> 4;
            int kk0 = (idx4 & 15) * 4;
            float4 w4 = *(const float4*)(W + (size_t)d * D + kh * 64 + kk0);
            lds_w[(kk0 + 0) * 129 + d] = w4.x;
            lds_w[(kk0 + 1) * 129 + d] = w4.y;
            lds_w[(kk0 + 2) * 129 + d] = w4.z;
            lds_w[(kk0 + 3) * 129 + d] = w4.w;
        }
#pragma unroll
        for (int it = 0; it < 2; ++it) {
            int idx4 = tid + it * 256;
            int row = idx4 >> 4;
            int kk0 = (idx4 & 15) * 4;
            size_t off = (size_t)(row0 + row) * D + kh * 64 + kk0;
            float4 hv = *(const float4*)(h + off);
            float4 av = *(const float4*)(aggr + off);
            float4 t4;
            t4.x = fmaf(ep1, hv.x, av.x);
            t4.y = fmaf(ep1, hv.y, av.y);
            t4.z = fmaf(ep1, hv.z, av.z);
            t4.w = fmaf(ep1, hv.w, av.w);
            *(float4*)(&lds_t[row * 68 + kk0]) = t4;
        }
        __syncthreads();

        for (int kk = 0; kk < 64; ++kk) {
            float tv[4], wv[4];
#pragma unroll
            for (int i = 0; i < 4; ++i) tv[i] = lds_t[(rg * 4 + i) * 68 + kk];
#pragma unroll
            for (int j = 0; j < 4; ++j) wv[j] = lds_w[kk * 129 + dl + 32 * j];
#pragma unroll
            for (int i = 0; i < 4; ++i)
#pragma unroll
                for (int j = 0; j < 4; ++j)
                    acc[i][j] = fmaf(tv[i], wv[j], acc[i][j]);
        }
    }

#pragma unroll
    for (int i = 0; i < 4; ++i) {
        int n = row0 + rg * 4 + i;
        const float* xr = x + (size_t)n * D;
        float* orow = out + (size_t)n * D;
#pragma unroll
        for (int j = 0; j < 4; ++j) {
            int d = dl + 32 * j;
            orow[d] = acc[i][j] + bias[d] + xr[d];
        }
    }
}

extern "C" void kernel_launch(void* const* d_in, const int* in_sizes, int n_in,
                              void* d_out, int out_size, void* d_ws, size_t ws_size,
                              hipStream_t stream)
{
    const float* x     = (const float*)d_in[0];
    const void*  ei    = d_in[1];
    const float* gamma = (const float*)d_in[2];
    const float* beta  = (const float*)d_in[3];
    const float* W     = (const float*)d_in[4];
    const float* bias  = (const float*)d_in[5];
    const float* eps_p = (const float*)d_in[6];
    float* out = (float*)d_out;

    char* ws = (char*)d_ws;
    size_t off = 0;
    float* h          = (float*)(ws + off); off += (size_t)N_NODES * D * 4;      // 51.2 MB
    int*   edges32    = (int*)(ws + off);   off += (size_t)2 * N_EDGES * 4;      // 12.8 MB
    int*   sorted_src = (int*)(ws + off);   off += (size_t)N_EDGES * 4;          //  6.4 MB
    int*   counts     = (int*)(ws + off);   off += (size_t)N_NODES * 4;          //  0.4 MB (reused as cursor)
    int*   pre        = (int*)(ws + off);   off += (size_t)N_NODES * 4;          //  0.4 MB
    int*   offsets    = (int*)(ws + off);   off += (size_t)(N_NODES + 4) * 4;    //  0.4 MB
    int*   bsum       = (int*)(ws + off);   off += 512 * 4;
    int*   flag       = (int*)(ws + off);   off += 4;

    const int NB_SCAN = (N_NODES + 255) / 256;  // 391

    ln_relu_kernel<<<N_NODES / 4, 256, 0, stream>>>(x, gamma, beta, h);
    detect_kernel<<<1, 1, 0, stream>>>((const int*)ei, flag);
    convert_edges_kernel<<<(2 * N_EDGES) / 256, 256, 0, stream>>>(ei, flag, edges32);
    hipMemsetAsync(counts, 0, (size_t)N_NODES * 4, stream);
    hist_kernel<<<N_EDGES / 256, 256, 0, stream>>>(edges32, counts);
    scan_partial_kernel<<<NB_SCAN, 256, 0, stream>>>(counts, pre, bsum);
    scan_block_kernel<<<1, 512, 0, stream>>>(bsum, NB_SCAN);
    finalize_kernel<<<(N_NODES + 256) / 256, 256, 0, stream>>>(pre, bsum, offsets, counts);
    place_kernel<<<N_EDGES / 256, 256, 0, stream>>>(edges32, counts, sorted_src);
    segsum_kernel<<<N_NODES / 4, 256, 0, stream>>>(h, offsets, sorted_src, out);
    out_gemm_kernel<<<N_NODES / 32, 256, 0, stream>>>(h, out, x, W, bias, eps_p, out);
}

// Round 3
// 343.028 us; speedup vs baseline: 8.0942x; 1.1633x over previous
//
#include <hip/hip_runtime.h>

#define N_NODES 100000
#define N_EDGES 1600000
#define D 128

// ---------------- Kernel 1: LayerNorm + ReLU (one wave per row, 4 rows/block) ----
__global__ __launch_bounds__(256) void ln_relu_kernel(
    const float* __restrict__ x, const float* __restrict__ gamma,
    const float* __restrict__ beta, float* __restrict__ h)
{
    int row  = blockIdx.x * 4 + (threadIdx.x >> 6);
    int lane = threadIdx.x & 63;
    const float* xr = x + (size_t)row * D;
    float2 v = *(const float2*)(xr + lane * 2);
    float s  = v.x + v.y;
    float sq = v.x * v.x + v.y * v.y;
#pragma unroll
    for (int m = 32; m >= 1; m >>= 1) {
        s  += __shfl_xor(s, m);
        sq += __shfl_xor(sq, m);
    }
    float mu   = s * (1.0f / D);
    float var  = sq * (1.0f / D) - mu * mu;
    float rstd = rsqrtf(var + 1e-5f);
    float g0 = gamma[lane * 2], g1 = gamma[lane * 2 + 1];
    float b0 = beta[lane * 2],  b1 = beta[lane * 2 + 1];
    float h0 = fmaxf(fmaf((v.x - mu) * rstd, g0, b0), 0.0f);
    float h1 = fmaxf(fmaf((v.y - mu) * rstd, g1, b1), 0.0f);
    *(float2*)(h + (size_t)row * D + lane * 2) = make_float2(h0, h1);
}

// ---------------- Kernel 1b: detect edge dtype (int64 vs int32 view) ------------
__global__ void detect_kernel(const int* __restrict__ e, int* __restrict__ flag)
{
    int z = 1;
    for (int i = 1; i < 128; i += 2) z &= (e[i] == 0) ? 1 : 0;
    *flag = z;  // 1 => int64 layout
}

// ---------------- Kernel 2: build per-dst linked chains --------------------------
// chain[e] = {src, next_edge}; head[d] = most recent edge targeting d (or -1).
// All stores coalesced; only the head exchange is random (400 KB array).
__global__ __launch_bounds__(256) void chain_build_kernel(
    const void* __restrict__ e_raw, const int* __restrict__ flag,
    int2* __restrict__ chain, int* __restrict__ head)
{
    int e = blockIdx.x * 256 + threadIdx.x;   // exactly N_EDGES threads
    int s, d;
    if (*flag) {
        s = (int)((const long long*)e_raw)[e];
        d = (int)((const long long*)e_raw)[N_EDGES + e];
    } else {
        s = ((const int*)e_raw)[e];
        d = ((const int*)e_raw)[N_EDGES + e];
    }
    int old = atomicExch(&head[d], e);
    chain[e] = make_int2(s, old);
}

// ---------------- Kernel 3: segment sum via chain walk — 2 nodes per wave --------
// msg = relu(h[src]) = h[src] since h >= 0. Each aggr row written exactly once.
__global__ __launch_bounds__(256) void chain_segsum_kernel(
    const float* __restrict__ h, const int* __restrict__ head,
    const int2* __restrict__ chain, float* __restrict__ aggr)
{
    int wid  = blockIdx.x * 4 + (threadIdx.x >> 6);
    int lane = threadIdx.x & 63;
    int n0 = wid * 2;
    int n1 = n0 + 1;
    int e0 = head[n0];
    int e1 = head[n1];
    float2 a0 = make_float2(0.0f, 0.0f);
    float2 a1 = make_float2(0.0f, 0.0f);
    while (e0 != -1 || e1 != -1) {
        int s0 = -1, s1 = -1;
        if (e0 != -1) { int2 c = chain[e0]; s0 = c.x; e0 = c.y; }
        if (e1 != -1) { int2 c = chain[e1]; s1 = c.x; e1 = c.y; }
        if (s0 != -1) {
            float2 v = *(const float2*)(h + (size_t)s0 * D + lane * 2);
            a0.x += v.x; a0.y += v.y;
        }
        if (s1 != -1) {
            float2 v = *(const float2*)(h + (size_t)s1 * D + lane * 2);
            a1.x += v.x; a1.y += v.y;
        }
    }
    *(float2*)(aggr + (size_t)n0 * D + lane * 2) = a0;
    *(float2*)(aggr + (size_t)n1 * D + lane * 2) = a1;
}

// ---------------- Kernel 4: out = ((1+eps)h + aggr) @ W^T + b + x ---------------
// aggr aliases `out`: each block reads only the 32 rows it later writes.
__global__ __launch_bounds__(256) void out_gemm_kernel(
    const float* __restrict__ h, const float* __restrict__ aggr,
    const float* __restrict__ x, const float* __restrict__ W,
    const float* __restrict__ bias, const float* __restrict__ eps_p,
    float* __restrict__ out)
{
    __shared__ float lds_w[64 * 129];
    __shared__ float lds_t[32 * 68];
    const int tid = threadIdx.x;
    const int dl  = tid & 31;
    const int rg  = tid >> 5;
    const int row0 = blockIdx.x * 32;
    const float ep1 = 1.0f + eps_p[0];
    float acc[4][4] = {};

    for (int kh = 0; kh < 2; ++kh) {
        if (kh) __syncthreads();
#pragma unroll
        for (int it = 0; it < 8; ++it) {
            int idx4 = tid + it * 256;
            int d   = idx4 >> 4;
            int kk0 = (idx4 & 15) * 4;
            float4 w4 = *(const float4*)(W + (size_t)d * D + kh * 64 + kk0);
            lds_w[(kk0 + 0) * 129 + d] = w4.x;
            lds_w[(kk0 + 1) * 129 + d] = w4.y;
            lds_w[(kk0 + 2) * 129 + d] = w4.z;
            lds_w[(kk0 + 3) * 129 + d] = w4.w;
        }
#pragma unroll
        for (int it = 0; it < 2; ++it) {
            int idx4 = tid + it * 256;
            int row = idx4 >> 4;
            int kk0 = (idx4 & 15) * 4;
            size_t off = (size_t)(row0 + row) * D + kh * 64 + kk0;
            float4 hv = *(const float4*)(h + off);
            float4 av = *(const float4*)(aggr + off);
            float4 t4;
            t4.x = fmaf(ep1, hv.x, av.x);
            t4.y = fmaf(ep1, hv.y, av.y);
            t4.z = fmaf(ep1, hv.z, av.z);
            t4.w = fmaf(ep1, hv.w, av.w);
            *(float4*)(&lds_t[row * 68 + kk0]) = t4;
        }
        __syncthreads();

        for (int kk = 0; kk < 64; ++kk) {
            float tv[4], wv[4];
#pragma unroll
            for (int i = 0; i < 4; ++i) tv[i] = lds_t[(rg * 4 + i) * 68 + kk];
#pragma unroll
            for (int j = 0; j < 4; ++j) wv[j] = lds_w[kk * 129 + dl + 32 * j];
#pragma unroll
            for (int i = 0; i < 4; ++i)
#pragma unroll
                for (int j = 0; j < 4; ++j)
                    acc[i][j] = fmaf(tv[i], wv[j], acc[i][j]);
        }
    }

#pragma unroll
    for (int i = 0; i < 4; ++i) {
        int n = row0 + rg * 4 + i;
        const float* xr = x + (size_t)n * D;
        float* orow = out + (size_t)n * D;
#pragma unroll
        for (int j = 0; j < 4; ++j) {
            int d = dl + 32 * j;
            orow[d] = acc[i][j] + bias[d] + xr[d];
        }
    }
}

extern "C" void kernel_launch(void* const* d_in, const int* in_sizes, int n_in,
                              void* d_out, int out_size, void* d_ws, size_t ws_size,
                              hipStream_t stream)
{
    const float* x     = (const float*)d_in[0];
    const void*  ei    = d_in[1];
    const float* gamma = (const float*)d_in[2];
    const float* beta  = (const float*)d_in[3];
    const float* W     = (const float*)d_in[4];
    const float* bias  = (const float*)d_in[5];
    const float* eps_p = (const float*)d_in[6];
    float* out = (float*)d_out;

    char* ws = (char*)d_ws;
    size_t off = 0;
    float* h     = (float*)(ws + off); off += (size_t)N_NODES * D * 4;   // 51.2 MB
    int2*  chain = (int2*)(ws + off);  off += (size_t)N_EDGES * 8;       // 12.8 MB
    int*   head  = (int*)(ws + off);   off += (size_t)N_NODES * 4;       //  0.4 MB
    int*   flag  = (int*)(ws + off);   off += 4;

    detect_kernel<<<1, 1, 0, stream>>>((const int*)ei, flag);
    hipMemsetAsync(head, 0xFF, (size_t)N_NODES * 4, stream);             // head = -1
    chain_build_kernel<<<N_EDGES / 256, 256, 0, stream>>>(ei, flag, chain, head);
    ln_relu_kernel<<<N_NODES / 4, 256, 0, stream>>>(x, gamma, beta, h);
    chain_segsum_kernel<<<N_NODES / 8, 256, 0, stream>>>(h, head, chain, out);
    out_gemm_kernel<<<N_NODES / 32, 256, 0, stream>>>(h, out, x, W, bias, eps_p, out);
}

// Round 5
// 336.766 us; speedup vs baseline: 8.2447x; 1.0186x over previous
//
#include <hip/hip_runtime.h>

#define N_NODES 100000
#define N_EDGES 1600000
#define D 128

typedef unsigned short ushort_t;
struct ushort4_t { ushort_t x, y, z, w; };
typedef float vf2 __attribute__((ext_vector_type(2)));
typedef float vf4 __attribute__((ext_vector_type(4)));

__device__ __forceinline__ ushort_t f2bf(float f) {
    unsigned u = __float_as_uint(f);
    unsigned r = (u + 0x7fffu + ((u >> 16) & 1u)) >> 16;   // RNE
    return (ushort_t)r;
}
__device__ __forceinline__ float bf2f(ushort_t b) {
    return __uint_as_float(((unsigned)b) << 16);
}

// ---------------- Kernel 1: LayerNorm + ReLU -> bf16 h ---------------------------
// 32 lanes per row (float4 loads), 2 rows per wave, 8 rows per block.
__global__ __launch_bounds__(256) void ln_relu_kernel(
    const float* __restrict__ x, const float* __restrict__ gamma,
    const float* __restrict__ beta, ushort_t* __restrict__ hb)
{
    int wave   = threadIdx.x >> 6;
    int half   = (threadIdx.x >> 5) & 1;
    int lane32 = threadIdx.x & 31;
    int row = blockIdx.x * 8 + wave * 2 + half;
    float4 v = ((const float4*)(x + (size_t)row * D))[lane32];
    float s  = (v.x + v.y) + (v.z + v.w);
    float sq = (v.x * v.x + v.y * v.y) + (v.z * v.z + v.w * v.w);
#pragma unroll
    for (int m = 16; m >= 1; m >>= 1) {        // stays within the 32-lane half
        s  += __shfl_xor(s, m);
        sq += __shfl_xor(sq, m);
    }
    float mu   = s * (1.0f / D);
    float var  = sq * (1.0f / D) - mu * mu;
    float rstd = rsqrtf(var + 1e-5f);
    float4 g = ((const float4*)gamma)[lane32];
    float4 b = ((const float4*)beta)[lane32];
    ushort4_t o;
    o.x = f2bf(fmaxf(fmaf((v.x - mu) * rstd, g.x, b.x), 0.0f));
    o.y = f2bf(fmaxf(fmaf((v.y - mu) * rstd, g.y, b.y), 0.0f));
    o.z = f2bf(fmaxf(fmaf((v.z - mu) * rstd, g.z, b.z), 0.0f));
    o.w = f2bf(fmaxf(fmaf((v.w - mu) * rstd, g.w, b.w), 0.0f));
    *(ushort4_t*)(hb + (size_t)row * D + lane32 * 4) = o;
}

// ---------------- Kernel 1b: detect edge dtype (int64 vs int32 view) ------------
__global__ void detect_kernel(const int* __restrict__ e, int* __restrict__ flag)
{
    int z = 1;
    for (int i = 1; i < 128; i += 2) z &= (e[i] == 0) ? 1 : 0;
    *flag = z;  // 1 => int64 layout
}

// ---------------- Kernel 2: build per-dst linked chains --------------------------
// chain[e] = src | (next << 32). All chain stores coalesced & nontemporal.
__global__ __launch_bounds__(256) void chain_build_kernel(
    const void* __restrict__ e_raw, const int* __restrict__ flag,
    long long* __restrict__ chain, int* __restrict__ head)
{
    int e = blockIdx.x * 256 + threadIdx.x;   // exactly N_EDGES threads
    int s, d;
    if (*flag) {
        s = (int)((const long long*)e_raw)[e];
        d = (int)((const long long*)e_raw)[N_EDGES + e];
    } else {
        s = ((const int*)e_raw)[e];
        d = ((const int*)e_raw)[N_EDGES + e];
    }
    int old = atomicExch(&head[d], e);
    long long packed = (unsigned int)s | ((long long)old << 32);
    __builtin_nontemporal_store(packed, &chain[e]);
}

// ---------------- Kernel 3: segment sum via chain walk (bf16 gather) -------------
// msg = relu(h[src]) = h[src] since h >= 0. Each aggr row written exactly once.
__global__ __launch_bounds__(256) void chain_segsum_kernel(
    const ushort_t* __restrict__ hb, const int* __restrict__ head,
    const long long* __restrict__ chain, float* __restrict__ aggr)
{
    int wid  = blockIdx.x * 4 + (threadIdx.x >> 6);
    int lane = threadIdx.x & 63;
    int n0 = wid * 2;
    int n1 = n0 + 1;
    int e0 = head[n0];
    int e1 = head[n1];
    float a0x = 0.0f, a0y = 0.0f, a1x = 0.0f, a1y = 0.0f;
    while (e0 != -1 || e1 != -1) {
        int s0 = -1, s1 = -1;
        if (e0 != -1) {
            long long c = __builtin_nontemporal_load(&chain[e0]);
            s0 = (int)(unsigned int)c;
            e0 = (int)(c >> 32);
        }
        if (e1 != -1) {
            long long c = __builtin_nontemporal_load(&chain[e1]);
            s1 = (int)(unsigned int)c;
            e1 = (int)(c >> 32);
        }
        if (s0 != -1) {
            unsigned p = *(const unsigned*)(hb + (size_t)s0 * D + lane * 2);
            a0x += bf2f((ushort_t)(p & 0xffffu));
            a0y += bf2f((ushort_t)(p >> 16));
        }
        if (s1 != -1) {
            unsigned p = *(const unsigned*)(hb + (size_t)s1 * D + lane * 2);
            a1x += bf2f((ushort_t)(p & 0xffffu));
            a1y += bf2f((ushort_t)(p >> 16));
        }
    }
    vf2 o0 = {a0x, a0y};
    vf2 o1 = {a1x, a1y};
    __builtin_nontemporal_store(o0, (vf2*)(aggr + (size_t)n0 * D + lane * 2));
    __builtin_nontemporal_store(o1, (vf2*)(aggr + (size_t)n1 * D + lane * 2));
}

// ---------------- Kernel 4: out = ((1+eps)h + aggr) @ W^T + b + x ---------------
// aggr aliases `out`: each block reads only the 32 rows it later writes.
__global__ __launch_bounds__(256) void out_gemm_kernel(
    const ushort_t* __restrict__ hb, const float* __restrict__ aggr,
    const float* __restrict__ x, const float* __restrict__ W,
    const float* __restrict__ bias, const float* __restrict__ eps_p,
    float* __restrict__ out)
{
    __shared__ float lds_w[64 * 129];
    __shared__ float lds_t[32 * 68];
    const int tid = threadIdx.x;
    const int dl  = tid & 31;
    const int rg  = tid >> 5;
    const int row0 = blockIdx.x * 32;
    const float ep1 = 1.0f + eps_p[0];
    float acc[4][4] = {};

    for (int kh = 0; kh < 2; ++kh) {
        if (kh) __syncthreads();
#pragma unroll
        for (int it = 0; it < 8; ++it) {
            int idx4 = tid + it * 256;
            int d   = idx4 >> 4;
            int kk0 = (idx4 & 15) * 4;
            float4 w4 = *(const float4*)(W + (size_t)d * D + kh * 64 + kk0);
            lds_w[(kk0 + 0) * 129 + d] = w4.x;
            lds_w[(kk0 + 1) * 129 + d] = w4.y;
            lds_w[(kk0 + 2) * 129 + d] = w4.z;
            lds_w[(kk0 + 3) * 129 + d] = w4.w;
        }
#pragma unroll
        for (int it = 0; it < 2; ++it) {
            int idx4 = tid + it * 256;
            int row = idx4 >> 4;
            int kk0 = (idx4 & 15) * 4;
            size_t off = (size_t)(row0 + row) * D + kh * 64 + kk0;
            ushort4_t hv = *(const ushort4_t*)(hb + off);
            vf4 av = __builtin_nontemporal_load((const vf4*)(aggr + off));
            float4 t4;
            t4.x = fmaf(ep1, bf2f(hv.x), av.x);
            t4.y = fmaf(ep1, bf2f(hv.y), av.y);
            t4.z = fmaf(ep1, bf2f(hv.z), av.z);
            t4.w = fmaf(ep1, bf2f(hv.w), av.w);
            *(float4*)(&lds_t[row * 68 + kk0]) = t4;
        }
        __syncthreads();

        for (int kk = 0; kk < 64; ++kk) {
            float tv[4], wv[4];
#pragma unroll
            for (int i = 0; i < 4; ++i) tv[i] = lds_t[(rg * 4 + i) * 68 + kk];
#pragma unroll
            for (int j = 0; j < 4; ++j) wv[j] = lds_w[kk * 129 + dl + 32 * j];
#pragma unroll
            for (int i = 0; i < 4; ++i)
#pragma unroll
                for (int j = 0; j < 4; ++j)
                    acc[i][j] = fmaf(tv[i], wv[j], acc[i][j]);
        }
    }

#pragma unroll
    for (int i = 0; i < 4; ++i) {
        int n = row0 + rg * 4 + i;
        const float* xr = x + (size_t)n * D;
        float* orow = out + (size_t)n * D;
#pragma unroll
        for (int j = 0; j < 4; ++j) {
            int d = dl + 32 * j;
            orow[d] = acc[i][j] + bias[d] + xr[d];
        }
    }
}

extern "C" void kernel_launch(void* const* d_in, const int* in_sizes, int n_in,
                              void* d_out, int out_size, void* d_ws, size_t ws_size,
                              hipStream_t stream)
{
    const float* x     = (const float*)d_in[0];
    const void*  ei    = d_in[1];
    const float* gamma = (const float*)d_in[2];
    const float* beta  = (const float*)d_in[3];
    const float* W     = (const float*)d_in[4];
    const float* bias  = (const float*)d_in[5];
    const float* eps_p = (const float*)d_in[6];
    float* out = (float*)d_out;

    char* ws = (char*)d_ws;
    size_t off = 0;
    ushort_t*  hb    = (ushort_t*)(ws + off);  off += (size_t)N_NODES * D * 2;  // 25.6 MB
    long long* chain = (long long*)(ws + off); off += (size_t)N_EDGES * 8;      // 12.8 MB
    int*       head  = (int*)(ws + off);       off += (size_t)N_NODES * 4;      //  0.4 MB
    int*       flag  = (int*)(ws + off);       off += 4;

    detect_kernel<<<1, 1, 0, stream>>>((const int*)ei, flag);
    (void)hipMemsetAsync(head, 0xFF, (size_t)N_NODES * 4, stream);              // head = -1
    chain_build_kernel<<<N_EDGES / 256, 256, 0, stream>>>(ei, flag, chain, head);
    ln_relu_kernel<<<N_NODES / 8, 256, 0, stream>>>(x, gamma, beta, hb);
    chain_segsum_kernel<<<N_NODES / 8, 256, 0, stream>>>(hb, head, chain, out);
    out_gemm_kernel<<<N_NODES / 32, 256, 0, stream>>>(hb, out, x, W, bias, eps_p, out);
}